// Round 9
// baseline (311.263 us; speedup 1.0000x reference)
//
#include <hip/hip_runtime.h>
#include <stdint.h>

#define NB 16
#define NS 4096
#define NH 16
#define NC 1024

// ---- workspace layout (float offsets) ----
#define OFF_QHP   0u          // 262144   qhp[cs16][b][d]
#define OFF_QK    262144u     // 262144   qk[b][h][c]
#define OFF_QB    524288u     // 256      qb[b][h]
#define OFF_FLAG  524544u     // 64       mask dtype flag
#define OFF_SP    524608u     // 32768    Sp[b][sb32][ph32]
#define OFF_S     557376u     // 512      S[p][b][h]
#define OFF_ATT   557888u     // 2097152  att[b][s][p*16+h] (unnormalized exp)
#define OFF_CTXP  2655040u    // 8388608  ctxp[ss16][p][b][h][c]
#define OFF_CTX   11043648u   // 524288   ctx[p][b][h][c] (normalized)
#define OFF_CON   11567936u   // 32768    concat[p][b][dm]

// Detect how the harness materialized the bool mask.
__global__ void k_maskprobe(const uint32_t* __restrict__ m, int* __restrict__ flag) {
    __shared__ int sf, sg;
    if (threadIdx.x == 0) { sf = 0; sg = 0; }
    __syncthreads();
    uint32_t x = m[threadIdx.x];
    if (x == 0x3F800000u) atomicOr(&sf, 1);
    else if (x > 1u) atomicOr(&sg, 1);
    __syncthreads();
    if (threadIdx.x == 0) *flag = sf ? 2 : (sg ? 1 : 0);
}

// qhp[cs][b][d] = sum_{c in cs-chunk} q[b][c] * Wq[c][d]
__global__ __launch_bounds__(128) void k_qh(
    const float* __restrict__ q, const float* __restrict__ Wq, float* __restrict__ qhp)
{
    __shared__ float qs[64*16];   // [c][b]
    int dz = blockIdx.x, cs = blockIdx.y;
    int tid = threadIdx.x;
    int d = dz*128 + tid;
#pragma unroll
    for (int j = 0; j < 2; ++j) {
        int idx = j*128 + tid;
        int b = idx >> 4, c4 = (idx & 15) << 2;
        float4 t = *(const float4*)(q + (size_t)b*NC + cs*64 + c4);
        qs[(c4+0)*16 + b] = t.x; qs[(c4+1)*16 + b] = t.y;
        qs[(c4+2)*16 + b] = t.z; qs[(c4+3)*16 + b] = t.w;
    }
    __syncthreads();
    float acc[16];
#pragma unroll
    for (int b = 0; b < 16; ++b) acc[b] = 0.f;
#pragma unroll 4
    for (int c = 0; c < 64; ++c) {
        float w = Wq[(size_t)(cs*64 + c)*NC + d];
        const float4* qr = (const float4*)(qs + c*16);
        float4 q0 = qr[0], q1 = qr[1], q2 = qr[2], q3 = qr[3];
        acc[0]  = fmaf(w, q0.x, acc[0]);  acc[1]  = fmaf(w, q0.y, acc[1]);
        acc[2]  = fmaf(w, q0.z, acc[2]);  acc[3]  = fmaf(w, q0.w, acc[3]);
        acc[4]  = fmaf(w, q1.x, acc[4]);  acc[5]  = fmaf(w, q1.y, acc[5]);
        acc[6]  = fmaf(w, q1.z, acc[6]);  acc[7]  = fmaf(w, q1.w, acc[7]);
        acc[8]  = fmaf(w, q2.x, acc[8]);  acc[9]  = fmaf(w, q2.y, acc[9]);
        acc[10] = fmaf(w, q2.z, acc[10]); acc[11] = fmaf(w, q2.w, acc[11]);
        acc[12] = fmaf(w, q3.x, acc[12]); acc[13] = fmaf(w, q3.y, acc[13]);
        acc[14] = fmaf(w, q3.z, acc[14]); acc[15] = fmaf(w, q3.w, acc[15]);
    }
#pragma unroll
    for (int b = 0; b < 16; ++b) qhp[((size_t)cs*16 + b)*NC + d] = acc[b];
}

// qk[b][h][c] = sum_d qh[b][h64+d]*Wk[c][h64+d];  qh = sum_cs qhp + bq. qb = qh_h . bk_h
__global__ __launch_bounds__(128) void k_qk(
    const float* __restrict__ qhp, const float* __restrict__ bq,
    const float* __restrict__ Wk, const float* __restrict__ bk,
    float* __restrict__ qko, float* __restrict__ qbv)
{
    int h = blockIdx.x;
    int c = blockIdx.y*128 + threadIdx.x;
    __shared__ float qs[16*64];   // [b][dd]
    for (int j = 0; j < 8; ++j) {
        int idx = j*128 + threadIdx.x;
        int b = idx >> 6, dd = idx & 63;
        float a = bq[h*64 + dd];
#pragma unroll
        for (int cs = 0; cs < 16; ++cs) a += qhp[((size_t)cs*16 + b)*NC + h*64 + dd];
        qs[idx] = a;
    }
    __syncthreads();
    const float* wr = Wk + (size_t)c*NC + h*64;
    float acc[16];
#pragma unroll
    for (int b = 0; b < 16; ++b) acc[b] = 0.f;
#pragma unroll 4
    for (int d = 0; d < 64; ++d) {
        float w = wr[d];
#pragma unroll
        for (int b = 0; b < 16; ++b) acc[b] = fmaf(qs[b*64 + d], w, acc[b]);
    }
#pragma unroll
    for (int b = 0; b < 16; ++b) qko[((size_t)b*NH + h)*NC + c] = acc[b];
    if (blockIdx.y == 0 && threadIdx.x < 16) {
        int b = threadIdx.x; float a = 0.f;
        for (int d = 0; d < 64; ++d) a = fmaf(qs[b*64 + d], bk[h*64 + d], a);
        qbv[b*NH + h] = a;
    }
}

// Fused scores+exp+mask+att+S.  grid (sb=32, b=16) = 512 blocks, 256 thr
// = 2 blocks/CU, 2 waves/SIMD.  Quad owns 8 rows x 4 heads:
//   tid bits: [1:0]=ph (c-phase), [3:2]=hg (head group), [7:4]=rg (row group).
// Lane ph reads bytes ph*16..+16 of each row's 64B k-window (full line use);
// ONE b128 q-read (4 h) feeds 8 rows => 0.5 B LDS per FMA.
#define QTS 20   // qt row stride (80B: 16B-aligned, conflict-free-ish)
__global__ __launch_bounds__(256) void k_scoresI(
    const float* __restrict__ kk, const float* __restrict__ qkm,
    const float* __restrict__ qbv, const void* __restrict__ mask,
    const int* __restrict__ flagp, float* __restrict__ att, float* __restrict__ Sp)
{
    __shared__ float qt[512*QTS];    // 40 KB [c_in_chunk][h]
    __shared__ float red[4][2][16];
    int sb = blockIdx.x, b = blockIdx.y;
    int tid = threadIdx.x;
    int ph = tid & 3, hg = (tid >> 2) & 3, rg = tid >> 4;
    int srow = sb*128 + rg*8;                 // quad's first row
    const float* kr = kk + ((size_t)b*NS + srow)*NC + ph*4;
    float acc[8][4];
#pragma unroll
    for (int i = 0; i < 8; ++i)
#pragma unroll
        for (int j = 0; j < 4; ++j) acc[i][j] = 0.f;

    for (int cz = 0; cz < 2; ++cz) {
        __syncthreads();
#pragma unroll
        for (int j = 0; j < 32; ++j) {        // stage 512c x 16h
            int idx = j*256 + tid;
            int h = idx >> 9, c = idx & 511;
            qt[c*QTS + h] = qkm[((size_t)b*NH + h)*NC + cz*512 + c];
        }
        __syncthreads();
        const float* kc0 = kr + cz*512;
        float4 kv[8], kn[8];
#pragma unroll
        for (int i = 0; i < 8; ++i) kv[i] = *(const float4*)(kc0 + i*NC);
        for (int w = 0; w < 32; ++w) {
            if (w < 31) {
#pragma unroll
                for (int i = 0; i < 8; ++i)
                    kn[i] = *(const float4*)(kc0 + i*NC + (w+1)*16);
            }
#pragma unroll
            for (int j = 0; j < 4; ++j) {
                const float* qp = qt + (w*16 + ph*4 + j)*QTS + hg*4;
                float4 qv = *(const float4*)qp;
#pragma unroll
                for (int i = 0; i < 8; ++i) {
                    float kc = (j == 0) ? kv[i].x : (j == 1) ? kv[i].y
                             : (j == 2) ? kv[i].z : kv[i].w;
                    acc[i][0] = fmaf(kc, qv.x, acc[i][0]);
                    acc[i][1] = fmaf(kc, qv.y, acc[i][1]);
                    acc[i][2] = fmaf(kc, qv.z, acc[i][2]);
                    acc[i][3] = fmaf(kc, qv.w, acc[i][3]);
                }
            }
#pragma unroll
            for (int i = 0; i < 8; ++i) kv[i] = kn[i];
        }
    }
    // quad butterfly over c-phases: all 4 lanes get full dots for 8 rows x 4 h
#pragma unroll
    for (int i = 0; i < 8; ++i)
#pragma unroll
        for (int j = 0; j < 4; ++j) {
            acc[i][j] += __shfl_xor(acc[i][j], 1, 64);
            acc[i][j] += __shfl_xor(acc[i][j], 2, 64);
        }
    // lane ph takes rows 2ph, 2ph+1 (static copy; no runtime reg indexing)
    float d0[4], d1[4];
    if (ph == 0) {
#pragma unroll
        for (int j = 0; j < 4; ++j) { d0[j] = acc[0][j]; d1[j] = acc[1][j]; }
    } else if (ph == 1) {
#pragma unroll
        for (int j = 0; j < 4; ++j) { d0[j] = acc[2][j]; d1[j] = acc[3][j]; }
    } else if (ph == 2) {
#pragma unroll
        for (int j = 0; j < 4; ++j) { d0[j] = acc[4][j]; d1[j] = acc[5][j]; }
    } else {
#pragma unroll
        for (int j = 0; j < 4; ++j) { d0[j] = acc[6][j]; d1[j] = acc[7][j]; }
    }
    int sA = srow + 2*ph, sB = sA + 1;
    int fl = *flagp;
    unsigned mA = 0, mB = 0;
    if (fl == 1) {
        const uint8_t* mp = (const uint8_t*)mask + (size_t)(b*NH + hg*4)*NS;
#pragma unroll
        for (int j = 0; j < 4; ++j) {
            if (mp[(size_t)j*NS + sA]) mA |= (1u << j);
            if (mp[(size_t)j*NS + sB]) mB |= (1u << j);
        }
    } else if (fl == 2) {
        const float* mp = (const float*)mask + (size_t)(b*NH + hg*4)*NS;
#pragma unroll
        for (int j = 0; j < 4; ++j) {
            if (mp[(size_t)j*NS + sA] != 0.f) mA |= (1u << j);
            if (mp[(size_t)j*NS + sB] != 0.f) mB |= (1u << j);
        }
    } else {
        const int* mp = (const int*)mask + (size_t)(b*NH + hg*4)*NS;
#pragma unroll
        for (int j = 0; j < 4; ++j) {
            if (mp[(size_t)j*NS + sA]) mA |= (1u << j);
            if (mp[(size_t)j*NS + sB]) mB |= (1u << j);
        }
    }
    float p0a[4], p1a[4], p0b[4], p1b[4], r0[4], r1[4];
#pragma unroll
    for (int j = 0; j < 4; ++j) {
        float qb = qbv[b*NH + hg*4 + j];
        float va = (d0[j] + qb) * 0.125f;
        float vb = (d1[j] + qb) * 0.125f;
        p0a[j] = __expf(va);  p1a[j] = (mA >> j & 1u) ? 1.0f : p0a[j];
        p0b[j] = __expf(vb);  p1b[j] = (mB >> j & 1u) ? 1.0f : p0b[j];
        r0[j] = p0a[j] + p0b[j];
        r1[j] = p1a[j] + p1b[j];
    }
    float* aA = att + ((size_t)b*NS + sA)*32 + hg*4;
    float* aB = att + ((size_t)b*NS + sB)*32 + hg*4;
    *(float4*)(aA)      = make_float4(p0a[0], p0a[1], p0a[2], p0a[3]);
    *(float4*)(aA + 16) = make_float4(p1a[0], p1a[1], p1a[2], p1a[3]);
    *(float4*)(aB)      = make_float4(p0b[0], p0b[1], p0b[2], p0b[3]);
    *(float4*)(aB + 16) = make_float4(p1b[0], p1b[1], p1b[2], p1b[3]);

    // S partials: sum over ph (xor 1,2) and rg-within-wave (xor 16,32)
#pragma unroll
    for (int j = 0; j < 4; ++j) {
        r0[j] += __shfl_xor(r0[j], 1, 64);  r1[j] += __shfl_xor(r1[j], 1, 64);
        r0[j] += __shfl_xor(r0[j], 2, 64);  r1[j] += __shfl_xor(r1[j], 2, 64);
        r0[j] += __shfl_xor(r0[j], 16, 64); r1[j] += __shfl_xor(r1[j], 16, 64);
        r0[j] += __shfl_xor(r0[j], 32, 64); r1[j] += __shfl_xor(r1[j], 32, 64);
    }
    int wv = tid >> 6;
    if ((tid & 51) == 0) {        // one lane per (wave, hg)
#pragma unroll
        for (int j = 0; j < 4; ++j) {
            red[wv][0][hg*4 + j] = r0[j];
            red[wv][1][hg*4 + j] = r1[j];
        }
    }
    __syncthreads();
    if (tid < 32) {
        int pa = tid >> 4, h = tid & 15;
        Sp[((size_t)b*32 + sb)*32 + tid] =
            red[0][pa][h] + red[1][pa][h] + red[2][pa][h] + red[3][pa][h];
    }
}

// S[p][b][h] = sum_sb Sp[b][sb][p*16+h]
__global__ void k_sred(const float* __restrict__ Sp, float* __restrict__ S) {
    int t = blockIdx.x*256 + threadIdx.x;   // 512 total
    int p = t >> 8, b = (t >> 4) & 15, h = t & 15;
    float a = 0.f;
#pragma unroll
    for (int sb = 0; sb < 32; ++sb) a += Sp[((size_t)b*32 + sb)*32 + p*16 + h];
    S[t] = a;
}

// ctx partials: ctxp[ss][p][b][h][c] = sum_{s in 256-row chunk} att[b][s][p,h]*v[b][s][c]
__global__ __launch_bounds__(256,2) void k_ctx(
    const float* __restrict__ v, const float* __restrict__ att, float* __restrict__ ctxp)
{
    __shared__ float al[64*32];
    __shared__ float buf[8192];
    int b = blockIdx.x & 15, ss = blockIdx.x >> 4;
    int cz = blockIdx.y;
    int tid = threadIdx.x, ct = tid & 63, rg = tid >> 6;
    int s1 = ss * 256;
    float acc[32][4];
#pragma unroll
    for (int i = 0; i < 32; ++i)
#pragma unroll
        for (int j = 0; j < 4; ++j) acc[i][j] = 0.f;

    for (int c0 = 0; c0 < 256; c0 += 64) {
        __syncthreads();
#pragma unroll
        for (int jj = 0; jj < 2; ++jj) {
            int idx = jj*256 + tid;
            ((float4*)al)[idx] = ((const float4*)(att + ((size_t)b*NS + s1 + c0)*32))[idx];
        }
        __syncthreads();
        for (int it = 0; it < 16; ++it) {
            int rl = c0 + it*4 + rg;
            float4 vv = *(const float4*)(v + ((size_t)b*NS + s1 + rl)*NC + cz*256 + ct*4);
            const float4* ar = (const float4*)(al + (it*4 + rg)*32);
#pragma unroll
            for (int u = 0; u < 8; ++u) {
                float4 aw = ar[u];
                acc[u*4+0][0] = fmaf(aw.x, vv.x, acc[u*4+0][0]);
                acc[u*4+0][1] = fmaf(aw.x, vv.y, acc[u*4+0][1]);
                acc[u*4+0][2] = fmaf(aw.x, vv.z, acc[u*4+0][2]);
                acc[u*4+0][3] = fmaf(aw.x, vv.w, acc[u*4+0][3]);
                acc[u*4+1][0] = fmaf(aw.y, vv.x, acc[u*4+1][0]);
                acc[u*4+1][1] = fmaf(aw.y, vv.y, acc[u*4+1][1]);
                acc[u*4+1][2] = fmaf(aw.y, vv.z, acc[u*4+1][2]);
                acc[u*4+1][3] = fmaf(aw.y, vv.w, acc[u*4+1][3]);
                acc[u*4+2][0] = fmaf(aw.z, vv.x, acc[u*4+2][0]);
                acc[u*4+2][1] = fmaf(aw.z, vv.y, acc[u*4+2][1]);
                acc[u*4+2][2] = fmaf(aw.z, vv.z, acc[u*4+2][2]);
                acc[u*4+2][3] = fmaf(aw.z, vv.w, acc[u*4+2][3]);
                acc[u*4+3][0] = fmaf(aw.w, vv.x, acc[u*4+3][0]);
                acc[u*4+3][1] = fmaf(aw.w, vv.y, acc[u*4+3][1]);
                acc[u*4+3][2] = fmaf(aw.w, vv.z, acc[u*4+3][2]);
                acc[u*4+3][3] = fmaf(aw.w, vv.w, acc[u*4+3][3]);
            }
        }
    }
    for (int pr = 0; pr < 4; ++pr) {
        __syncthreads();
#pragma unroll
        for (int u = 0; u < 8; ++u) {
            int ph = pr*8 + u;
            float4 t; t.x = acc[ph][0]; t.y = acc[ph][1]; t.z = acc[ph][2]; t.w = acc[ph][3];
            ((float4*)buf)[(rg*8 + u)*64 + ct] = t;
        }
        __syncthreads();
#pragma unroll
        for (int kx = 0; kx < 2; ++kx) {
            int i = kx*256 + tid;
            int u2 = i >> 6, c2 = i & 63;
            float4 s = ((float4*)buf)[(size_t)(0*8 + u2)*64 + c2];
#pragma unroll
            for (int r2 = 1; r2 < 4; ++r2) {
                float4 t = ((float4*)buf)[(size_t)(r2*8 + u2)*64 + c2];
                s.x += t.x; s.y += t.y; s.z += t.z; s.w += t.w;
            }
            int ph = pr*8 + u2, p = ph >> 4, h = ph & 15;
            *(float4*)(ctxp + ((((size_t)ss*2 + p)*NB + b)*NH + h)*NC + cz*256 + c2*4) = s;
        }
    }
}

// reduce ss partials + normalize by S
__global__ void k_ctxred(const float* __restrict__ ctxp, const float* __restrict__ S,
                         float* __restrict__ ctx) {
    size_t i = (size_t)blockIdx.x * 256 + threadIdx.x;
    float a = 0.f;
#pragma unroll
    for (int ss = 0; ss < 16; ++ss) a += ctxp[(size_t)ss*524288 + i];
    ctx[i] = a / S[i >> 10];
}

// concat[p][b][d] = ctx[p][b][h(d)][:] . Wv[:, d] + bv[d]
__global__ __launch_bounds__(256) void k_outh(
    const float* __restrict__ ctx, const float* __restrict__ Wv,
    const float* __restrict__ bv, float* __restrict__ con)
{
    int b = blockIdx.y, p = blockIdx.z;
    int d = blockIdx.x*256 + threadIdx.x;
    int h0 = blockIdx.x*4;
    __shared__ float cl[4*NC];
    for (int i = threadIdx.x; i < 4*NC; i += 256)
        cl[i] = ctx[(((size_t)p*NB + b)*NH + h0 + (i >> 10))*NC + (i & 1023)];
    __syncthreads();
    const float* c2 = cl + ((threadIdx.x >> 6) << 10);
    float a0=0.f,a1=0.f,a2=0.f,a3=0.f;
    for (int c = 0; c < NC; c += 4) {
        a0 = fmaf(c2[c+0], Wv[(size_t)(c+0)*NC + d], a0);
        a1 = fmaf(c2[c+1], Wv[(size_t)(c+1)*NC + d], a1);
        a2 = fmaf(c2[c+2], Wv[(size_t)(c+2)*NC + d], a2);
        a3 = fmaf(c2[c+3], Wv[(size_t)(c+3)*NC + d], a3);
    }
    con[((size_t)p*NB + b)*NC + d] = (a0+a1)+(a2+a3) + bv[d];
}

// out[p][b][o] = concat[p][b][:] . Wo[:, o] + bo[o]
__global__ __launch_bounds__(256) void k_out(
    const float* __restrict__ con, const float* __restrict__ Wo,
    const float* __restrict__ bo, float* __restrict__ out)
{
    int b = blockIdx.y, p = blockIdx.z;
    int o = blockIdx.x*256 + threadIdx.x;
    __shared__ float cl[NC];
    for (int i = threadIdx.x; i < NC; i += 256)
        cl[i] = con[((size_t)p*NB + b)*NC + i];
    __syncthreads();
    float a0=0.f,a1=0.f,a2=0.f,a3=0.f;
    for (int m = 0; m < NC; m += 4) {
        a0 = fmaf(cl[m+0], Wo[(size_t)(m+0)*NC + o], a0);
        a1 = fmaf(cl[m+1], Wo[(size_t)(m+1)*NC + o], a1);
        a2 = fmaf(cl[m+2], Wo[(size_t)(m+2)*NC + o], a2);
        a3 = fmaf(cl[m+3], Wo[(size_t)(m+3)*NC + o], a3);
    }
    out[(size_t)p*NB*NC + (size_t)b*NC + o] = (a0+a1)+(a2+a3) + bo[o];
}

extern "C" void kernel_launch(void* const* d_in, const int* in_sizes, int n_in,
                              void* d_out, int out_size, void* d_ws, size_t ws_size,
                              hipStream_t stream)
{
    (void)in_sizes; (void)n_in; (void)out_size; (void)ws_size;
    const float* q  = (const float*)d_in[0];
    const float* k  = (const float*)d_in[1];
    const float* v  = (const float*)d_in[2];
    const float* Wq = (const float*)d_in[3];
    const float* bq = (const float*)d_in[4];
    const float* Wk = (const float*)d_in[5];
    const float* bk = (const float*)d_in[6];
    const float* Wv = (const float*)d_in[7];
    const float* bv = (const float*)d_in[8];
    const float* Wo = (const float*)d_in[9];
    const float* bo = (const float*)d_in[10];
    const void*  mk = d_in[11];

    float* ws   = (float*)d_ws;
    float* qhp  = ws + OFF_QHP;
    float* qkv  = ws + OFF_QK;
    float* qbv  = ws + OFF_QB;
    int*   flg  = (int*)(ws + OFF_FLAG);
    float* Sp   = ws + OFF_SP;
    float* S    = ws + OFF_S;
    float* att  = ws + OFF_ATT;
    float* ctxp = ws + OFF_CTXP;
    float* ctx  = ws + OFF_CTX;
    float* con  = ws + OFF_CON;
    float* out  = (float*)d_out;

    k_maskprobe<<<1, 1024, 0, stream>>>((const uint32_t*)mk, flg);
    k_qh<<<dim3(8, 16), 128, 0, stream>>>(q, Wq, qhp);
    k_qk<<<dim3(16, 8), 128, 0, stream>>>(qhp, bq, Wk, bk, qkv, qbv);
    k_scoresI<<<dim3(32, 16), 256, 0, stream>>>(k, qkv, qbv, mk, flg, att, Sp);
    k_sred<<<2, 256, 0, stream>>>(Sp, S);
    k_ctx<<<dim3(256, 4), 256, 0, stream>>>(v, att, ctxp);
    k_ctxred<<<2048, 256, 0, stream>>>(ctxp, S, ctx);
    k_outh<<<dim3(4, NB, 2), 256, 0, stream>>>(ctx, Wv, bv, con);
    k_out<<<dim3(4, NB, 2), 256, 0, stream>>>(con, Wo, bo, out);
}

// Round 10
// 309.763 us; speedup vs baseline: 1.0048x; 1.0048x over previous
//
#include <hip/hip_runtime.h>
#include <stdint.h>

#define NB 16
#define NS 4096
#define NH 16
#define NC 1024

// ---- workspace layout (float offsets) ----
#define OFF_QHP   0u          // 262144   qhp[cs16][b][d]
#define OFF_QK    262144u     // 262144   qk[b][h][c]
#define OFF_QB    524288u     // 256      qb[b][h]
#define OFF_SP    524608u     // 16384    Sp[b][sb32][ph32]
#define OFF_ATT   540992u     // 2097152  att[b][s][p*16+h] (unnormalized exp)
#define OFF_CTXP  2638144u    // 8388608  ctxp[ss16][p][b][h][c]
#define OFF_CON   11026752u   // 32768    concat[p][b][dm]

// qhp[cs][b][d] = sum_{c in cs-chunk} q[b][c] * Wq[c][d]
__global__ __launch_bounds__(128) void k_qh(
    const float* __restrict__ q, const float* __restrict__ Wq, float* __restrict__ qhp)
{
    __shared__ float qs[64*16];   // [c][b]
    int dz = blockIdx.x, cs = blockIdx.y;
    int tid = threadIdx.x;
    int d = dz*128 + tid;
#pragma unroll
    for (int j = 0; j < 2; ++j) {
        int idx = j*128 + tid;
        int b = idx >> 4, c4 = (idx & 15) << 2;
        float4 t = *(const float4*)(q + (size_t)b*NC + cs*64 + c4);
        qs[(c4+0)*16 + b] = t.x; qs[(c4+1)*16 + b] = t.y;
        qs[(c4+2)*16 + b] = t.z; qs[(c4+3)*16 + b] = t.w;
    }
    __syncthreads();
    float acc[16];
#pragma unroll
    for (int b = 0; b < 16; ++b) acc[b] = 0.f;
#pragma unroll 4
    for (int c = 0; c < 64; ++c) {
        float w = Wq[(size_t)(cs*64 + c)*NC + d];
        const float4* qr = (const float4*)(qs + c*16);
        float4 q0 = qr[0], q1 = qr[1], q2 = qr[2], q3 = qr[3];
        acc[0]  = fmaf(w, q0.x, acc[0]);  acc[1]  = fmaf(w, q0.y, acc[1]);
        acc[2]  = fmaf(w, q0.z, acc[2]);  acc[3]  = fmaf(w, q0.w, acc[3]);
        acc[4]  = fmaf(w, q1.x, acc[4]);  acc[5]  = fmaf(w, q1.y, acc[5]);
        acc[6]  = fmaf(w, q1.z, acc[6]);  acc[7]  = fmaf(w, q1.w, acc[7]);
        acc[8]  = fmaf(w, q2.x, acc[8]);  acc[9]  = fmaf(w, q2.y, acc[9]);
        acc[10] = fmaf(w, q2.z, acc[10]); acc[11] = fmaf(w, q2.w, acc[11]);
        acc[12] = fmaf(w, q3.x, acc[12]); acc[13] = fmaf(w, q3.y, acc[13]);
        acc[14] = fmaf(w, q3.z, acc[14]); acc[15] = fmaf(w, q3.w, acc[15]);
    }
#pragma unroll
    for (int b = 0; b < 16; ++b) qhp[((size_t)cs*16 + b)*NC + d] = acc[b];
}

// qk[b][h][c] = sum_d qh[b][h64+d]*Wk[c][h64+d];  qh = sum_cs qhp + bq. qb = qh_h . bk_h
__global__ __launch_bounds__(128) void k_qk(
    const float* __restrict__ qhp, const float* __restrict__ bq,
    const float* __restrict__ Wk, const float* __restrict__ bk,
    float* __restrict__ qko, float* __restrict__ qbv)
{
    int h = blockIdx.x;
    int c = blockIdx.y*128 + threadIdx.x;
    __shared__ float qs[16*64];   // [b][dd]
    for (int j = 0; j < 8; ++j) {
        int idx = j*128 + threadIdx.x;
        int b = idx >> 6, dd = idx & 63;
        float a = bq[h*64 + dd];
#pragma unroll
        for (int cs = 0; cs < 16; ++cs) a += qhp[((size_t)cs*16 + b)*NC + h*64 + dd];
        qs[idx] = a;
    }
    __syncthreads();
    const float* wr = Wk + (size_t)c*NC + h*64;
    float acc[16];
#pragma unroll
    for (int b = 0; b < 16; ++b) acc[b] = 0.f;
#pragma unroll 4
    for (int d = 0; d < 64; ++d) {
        float w = wr[d];
#pragma unroll
        for (int b = 0; b < 16; ++b) acc[b] = fmaf(qs[b*64 + d], w, acc[b]);
    }
#pragma unroll
    for (int b = 0; b < 16; ++b) qko[((size_t)b*NH + h)*NC + c] = acc[b];
    if (blockIdx.y == 0 && threadIdx.x < 16) {
        int b = threadIdx.x; float a = 0.f;
        for (int d = 0; d < 64; ++d) a = fmaf(qs[b*64 + d], bk[h*64 + d], a);
        qbv[b*NH + h] = a;
    }
}

// Fused scores+exp+mask+att+S.  grid (sb=32, b=16) = 512 blocks, 256 thr.
// Quad owns 8 rows x 4 heads; lane ph covers c-phase; one b128 q-read feeds
// 8 rows (0.5 B LDS/FMA).  Depth-2 k-prefetch (3 rotating buffers).
// Mask dtype probed inline from the first 32 dwords (uniform loads).
#define QTS 20
#define SCOMP(BUF, W)                                                          \
    _Pragma("unroll")                                                          \
    for (int j = 0; j < 4; ++j) {                                              \
        const float* qp = qt + ((W)*16 + ph*4 + j)*QTS + hg*4;                 \
        float4 qv = *(const float4*)qp;                                        \
        _Pragma("unroll")                                                      \
        for (int i = 0; i < 8; ++i) {                                          \
            float kc = (j == 0) ? BUF[i].x : (j == 1) ? BUF[i].y               \
                     : (j == 2) ? BUF[i].z : BUF[i].w;                         \
            acc[i][0] = fmaf(kc, qv.x, acc[i][0]);                             \
            acc[i][1] = fmaf(kc, qv.y, acc[i][1]);                             \
            acc[i][2] = fmaf(kc, qv.z, acc[i][2]);                             \
            acc[i][3] = fmaf(kc, qv.w, acc[i][3]);                             \
        }                                                                      \
    }
__global__ __launch_bounds__(256) void k_scoresI2(
    const float* __restrict__ kk, const float* __restrict__ qkm,
    const float* __restrict__ qbv, const void* __restrict__ mask,
    float* __restrict__ att, float* __restrict__ Sp)
{
    __shared__ float qt[512*QTS];    // 40 KB [c_in_chunk][h]
    __shared__ float red[4][2][16];
    int sb = blockIdx.x, b = blockIdx.y;
    int tid = threadIdx.x;
    int ph = tid & 3, hg = (tid >> 2) & 3, rg = tid >> 4;
    int srow = sb*128 + rg*8;

    // inline mask dtype probe: 0=int32, 1=bytes, 2=float32
    int fl;
    {
        const uint4* mw = (const uint4*)mask;
        unsigned f = 0u, g = 0u;
#pragma unroll
        for (int j = 0; j < 8; ++j) {
            uint4 m4 = mw[j];
            f |= (m4.x == 0x3F800000u) | (m4.y == 0x3F800000u)
               | (m4.z == 0x3F800000u) | (m4.w == 0x3F800000u);
            g |= ((m4.x > 1u) & (m4.x != 0x3F800000u))
               | ((m4.y > 1u) & (m4.y != 0x3F800000u))
               | ((m4.z > 1u) & (m4.z != 0x3F800000u))
               | ((m4.w > 1u) & (m4.w != 0x3F800000u));
        }
        fl = f ? 2 : (g ? 1 : 0);
    }

    const float* kr = kk + ((size_t)b*NS + srow)*NC + ph*4;
    float acc[8][4];
#pragma unroll
    for (int i = 0; i < 8; ++i)
#pragma unroll
        for (int j = 0; j < 4; ++j) acc[i][j] = 0.f;

    for (int cz = 0; cz < 2; ++cz) {
        __syncthreads();
#pragma unroll
        for (int j = 0; j < 32; ++j) {        // stage 512c x 16h
            int idx = j*256 + tid;
            int h = idx >> 9, c = idx & 511;
            qt[c*QTS + h] = qkm[((size_t)b*NH + h)*NC + cz*512 + c];
        }
        __syncthreads();
        const float* kc0 = kr + cz*512;
        float4 A[8], B[8], T[8];
#pragma unroll
        for (int i = 0; i < 8; ++i) A[i] = *(const float4*)(kc0 + i*NC);
#pragma unroll
        for (int i = 0; i < 8; ++i) B[i] = *(const float4*)(kc0 + i*NC + 16);
        for (int w = 0; w < 32; w += 2) {
            if (w + 2 < 32) {
#pragma unroll
                for (int i = 0; i < 8; ++i)
                    T[i] = *(const float4*)(kc0 + i*NC + (w+2)*16);
            }
            SCOMP(A, w);
            if (w + 3 < 32) {
#pragma unroll
                for (int i = 0; i < 8; ++i)
                    A[i] = *(const float4*)(kc0 + i*NC + (w+3)*16);
            }
            SCOMP(B, (w+1));
#pragma unroll
            for (int i = 0; i < 8; ++i) { B[i] = A[i]; A[i] = T[i]; }
        }
    }
    // quad butterfly over c-phases
#pragma unroll
    for (int i = 0; i < 8; ++i)
#pragma unroll
        for (int j = 0; j < 4; ++j) {
            acc[i][j] += __shfl_xor(acc[i][j], 1, 64);
            acc[i][j] += __shfl_xor(acc[i][j], 2, 64);
        }
    // lane ph takes rows 2ph, 2ph+1 (static copies)
    float d0[4], d1[4];
    if (ph == 0) {
#pragma unroll
        for (int j = 0; j < 4; ++j) { d0[j] = acc[0][j]; d1[j] = acc[1][j]; }
    } else if (ph == 1) {
#pragma unroll
        for (int j = 0; j < 4; ++j) { d0[j] = acc[2][j]; d1[j] = acc[3][j]; }
    } else if (ph == 2) {
#pragma unroll
        for (int j = 0; j < 4; ++j) { d0[j] = acc[4][j]; d1[j] = acc[5][j]; }
    } else {
#pragma unroll
        for (int j = 0; j < 4; ++j) { d0[j] = acc[6][j]; d1[j] = acc[7][j]; }
    }
    int sA = srow + 2*ph, sB = sA + 1;
    unsigned mA = 0, mB = 0;
    if (fl == 1) {
        const uint8_t* mp = (const uint8_t*)mask + (size_t)(b*NH + hg*4)*NS;
#pragma unroll
        for (int j = 0; j < 4; ++j) {
            if (mp[(size_t)j*NS + sA]) mA |= (1u << j);
            if (mp[(size_t)j*NS + sB]) mB |= (1u << j);
        }
    } else if (fl == 2) {
        const float* mp = (const float*)mask + (size_t)(b*NH + hg*4)*NS;
#pragma unroll
        for (int j = 0; j < 4; ++j) {
            if (mp[(size_t)j*NS + sA] != 0.f) mA |= (1u << j);
            if (mp[(size_t)j*NS + sB] != 0.f) mB |= (1u << j);
        }
    } else {
        const int* mp = (const int*)mask + (size_t)(b*NH + hg*4)*NS;
#pragma unroll
        for (int j = 0; j < 4; ++j) {
            if (mp[(size_t)j*NS + sA]) mA |= (1u << j);
            if (mp[(size_t)j*NS + sB]) mB |= (1u << j);
        }
    }
    float p0a[4], p1a[4], p0b[4], p1b[4], r0[4], r1[4];
#pragma unroll
    for (int j = 0; j < 4; ++j) {
        float qb = qbv[b*NH + hg*4 + j];
        float va = (d0[j] + qb) * 0.125f;
        float vb = (d1[j] + qb) * 0.125f;
        p0a[j] = __expf(va);  p1a[j] = (mA >> j & 1u) ? 1.0f : p0a[j];
        p0b[j] = __expf(vb);  p1b[j] = (mB >> j & 1u) ? 1.0f : p0b[j];
        r0[j] = p0a[j] + p0b[j];
        r1[j] = p1a[j] + p1b[j];
    }
    float* aA = att + ((size_t)b*NS + sA)*32 + hg*4;
    float* aB = att + ((size_t)b*NS + sB)*32 + hg*4;
    *(float4*)(aA)      = make_float4(p0a[0], p0a[1], p0a[2], p0a[3]);
    *(float4*)(aA + 16) = make_float4(p1a[0], p1a[1], p1a[2], p1a[3]);
    *(float4*)(aB)      = make_float4(p0b[0], p0b[1], p0b[2], p0b[3]);
    *(float4*)(aB + 16) = make_float4(p1b[0], p1b[1], p1b[2], p1b[3]);

    // S partials: sum over ph (xor 1,2) and rg-within-wave (xor 16,32)
#pragma unroll
    for (int j = 0; j < 4; ++j) {
        r0[j] += __shfl_xor(r0[j], 1, 64);  r1[j] += __shfl_xor(r1[j], 1, 64);
        r0[j] += __shfl_xor(r0[j], 2, 64);  r1[j] += __shfl_xor(r1[j], 2, 64);
        r0[j] += __shfl_xor(r0[j], 16, 64); r1[j] += __shfl_xor(r1[j], 16, 64);
        r0[j] += __shfl_xor(r0[j], 32, 64); r1[j] += __shfl_xor(r1[j], 32, 64);
    }
    int wv = tid >> 6;
    if ((tid & 51) == 0) {
#pragma unroll
        for (int j = 0; j < 4; ++j) {
            red[wv][0][hg*4 + j] = r0[j];
            red[wv][1][hg*4 + j] = r1[j];
        }
    }
    __syncthreads();
    if (tid < 32) {
        int pa = tid >> 4, h = tid & 15;
        Sp[((size_t)b*32 + sb)*32 + tid] =
            red[0][pa][h] + red[1][pa][h] + red[2][pa][h] + red[3][pa][h];
    }
}

// ctx partials: ctxp[ss][p][b][h][c] = sum_{s in 256-row chunk} att[b][s][p,h]*v[b][s][c]
__global__ __launch_bounds__(256,2) void k_ctx(
    const float* __restrict__ v, const float* __restrict__ att, float* __restrict__ ctxp)
{
    __shared__ float al[64*32];
    __shared__ float buf[8192];
    int b = blockIdx.x & 15, ss = blockIdx.x >> 4;
    int cz = blockIdx.y;
    int tid = threadIdx.x, ct = tid & 63, rg = tid >> 6;
    int s1 = ss * 256;
    float acc[32][4];
#pragma unroll
    for (int i = 0; i < 32; ++i)
#pragma unroll
        for (int j = 0; j < 4; ++j) acc[i][j] = 0.f;

    for (int c0 = 0; c0 < 256; c0 += 64) {
        __syncthreads();
#pragma unroll
        for (int jj = 0; jj < 2; ++jj) {
            int idx = jj*256 + tid;
            ((float4*)al)[idx] = ((const float4*)(att + ((size_t)b*NS + s1 + c0)*32))[idx];
        }
        __syncthreads();
        for (int it = 0; it < 16; ++it) {
            int rl = c0 + it*4 + rg;
            float4 vv = *(const float4*)(v + ((size_t)b*NS + s1 + rl)*NC + cz*256 + ct*4);
            const float4* ar = (const float4*)(al + (it*4 + rg)*32);
#pragma unroll
            for (int u = 0; u < 8; ++u) {
                float4 aw = ar[u];
                acc[u*4+0][0] = fmaf(aw.x, vv.x, acc[u*4+0][0]);
                acc[u*4+0][1] = fmaf(aw.x, vv.y, acc[u*4+0][1]);
                acc[u*4+0][2] = fmaf(aw.x, vv.z, acc[u*4+0][2]);
                acc[u*4+0][3] = fmaf(aw.x, vv.w, acc[u*4+0][3]);
                acc[u*4+1][0] = fmaf(aw.y, vv.x, acc[u*4+1][0]);
                acc[u*4+1][1] = fmaf(aw.y, vv.y, acc[u*4+1][1]);
                acc[u*4+1][2] = fmaf(aw.y, vv.z, acc[u*4+1][2]);
                acc[u*4+1][3] = fmaf(aw.y, vv.w, acc[u*4+1][3]);
                acc[u*4+2][0] = fmaf(aw.z, vv.x, acc[u*4+2][0]);
                acc[u*4+2][1] = fmaf(aw.z, vv.y, acc[u*4+2][1]);
                acc[u*4+2][2] = fmaf(aw.z, vv.z, acc[u*4+2][2]);
                acc[u*4+2][3] = fmaf(aw.z, vv.w, acc[u*4+2][3]);
                acc[u*4+3][0] = fmaf(aw.w, vv.x, acc[u*4+3][0]);
                acc[u*4+3][1] = fmaf(aw.w, vv.y, acc[u*4+3][1]);
                acc[u*4+3][2] = fmaf(aw.w, vv.z, acc[u*4+3][2]);
                acc[u*4+3][3] = fmaf(aw.w, vv.w, acc[u*4+3][3]);
            }
        }
    }
    for (int pr = 0; pr < 4; ++pr) {
        __syncthreads();
#pragma unroll
        for (int u = 0; u < 8; ++u) {
            int ph = pr*8 + u;
            float4 t; t.x = acc[ph][0]; t.y = acc[ph][1]; t.z = acc[ph][2]; t.w = acc[ph][3];
            ((float4*)buf)[(rg*8 + u)*64 + ct] = t;
        }
        __syncthreads();
#pragma unroll
        for (int kx = 0; kx < 2; ++kx) {
            int i = kx*256 + tid;
            int u2 = i >> 6, c2 = i & 63;
            float4 s = ((float4*)buf)[(size_t)(0*8 + u2)*64 + c2];
#pragma unroll
            for (int r2 = 1; r2 < 4; ++r2) {
                float4 t = ((float4*)buf)[(size_t)(r2*8 + u2)*64 + c2];
                s.x += t.x; s.y += t.y; s.z += t.z; s.w += t.w;
            }
            int ph = pr*8 + u2, p = ph >> 4, h = ph & 15;
            *(float4*)(ctxp + ((((size_t)ss*2 + p)*NB + b)*NH + h)*NC + cz*256 + c2*4) = s;
        }
    }
}

// Fused: slab-reduce ctxp + S-normalize + Wv GEMV + bias -> concat[p][b][d]
__global__ __launch_bounds__(256) void k_outhN(
    const float* __restrict__ ctxp, const float* __restrict__ Sp,
    const float* __restrict__ Wv, const float* __restrict__ bv,
    float* __restrict__ con)
{
    int b = blockIdx.y, p = blockIdx.z;
    int dx = blockIdx.x;
    int d = dx*256 + threadIdx.x;
    int h0 = dx*4;
    __shared__ float cl[4*NC];
    float Sinv[4];
#pragma unroll
    for (int j = 0; j < 4; ++j) {
        float a = 0.f;
        for (int sb = 0; sb < 32; ++sb)
            a += Sp[((size_t)b*32 + sb)*32 + p*16 + h0 + j];
        Sinv[j] = 1.f / a;
    }
#pragma unroll
    for (int hh = 0; hh < 4; ++hh) {
        for (int cc = threadIdx.x; cc < NC; cc += 256) {
            float a = 0.f;
#pragma unroll
            for (int ss = 0; ss < 16; ++ss)
                a += ctxp[((((size_t)ss*2 + p)*NB + b)*NH + h0 + hh)*NC + cc];
            cl[hh*NC + cc] = a * Sinv[hh];
        }
    }
    __syncthreads();
    const float* c2 = cl + ((threadIdx.x >> 6) << 10);
    float a0=0.f,a1=0.f,a2=0.f,a3=0.f;
    for (int c = 0; c < NC; c += 4) {
        a0 = fmaf(c2[c+0], Wv[(size_t)(c+0)*NC + d], a0);
        a1 = fmaf(c2[c+1], Wv[(size_t)(c+1)*NC + d], a1);
        a2 = fmaf(c2[c+2], Wv[(size_t)(c+2)*NC + d], a2);
        a3 = fmaf(c2[c+3], Wv[(size_t)(c+3)*NC + d], a3);
    }
    con[((size_t)p*NB + b)*NC + d] = (a0+a1)+(a2+a3) + bv[d];
}

// out[p][b][o] = concat[p][b][:] . Wo[:, o] + bo[o]
__global__ __launch_bounds__(256) void k_out(
    const float* __restrict__ con, const float* __restrict__ Wo,
    const float* __restrict__ bo, float* __restrict__ out)
{
    int b = blockIdx.y, p = blockIdx.z;
    int o = blockIdx.x*256 + threadIdx.x;
    __shared__ float cl[NC];
    for (int i = threadIdx.x; i < NC; i += 256)
        cl[i] = con[((size_t)p*NB + b)*NC + i];
    __syncthreads();
    float a0=0.f,a1=0.f,a2=0.f,a3=0.f;
    for (int m = 0; m < NC; m += 4) {
        a0 = fmaf(cl[m+0], Wo[(size_t)(m+0)*NC + o], a0);
        a1 = fmaf(cl[m+1], Wo[(size_t)(m+1)*NC + o], a1);
        a2 = fmaf(cl[m+2], Wo[(size_t)(m+2)*NC + o], a2);
        a3 = fmaf(cl[m+3], Wo[(size_t)(m+3)*NC + o], a3);
    }
    out[(size_t)p*NB*NC + (size_t)b*NC + o] = (a0+a1)+(a2+a3) + bo[o];
}

extern "C" void kernel_launch(void* const* d_in, const int* in_sizes, int n_in,
                              void* d_out, int out_size, void* d_ws, size_t ws_size,
                              hipStream_t stream)
{
    (void)in_sizes; (void)n_in; (void)out_size; (void)ws_size;
    const float* q  = (const float*)d_in[0];
    const float* k  = (const float*)d_in[1];
    const float* v  = (const float*)d_in[2];
    const float* Wq = (const float*)d_in[3];
    const float* bq = (const float*)d_in[4];
    const float* Wk = (const float*)d_in[5];
    const float* bk = (const float*)d_in[6];
    const float* Wv = (const float*)d_in[7];
    const float* bv = (const float*)d_in[8];
    const float* Wo = (const float*)d_in[9];
    const float* bo = (const float*)d_in[10];
    const void*  mk = d_in[11];

    float* ws   = (float*)d_ws;
    float* qhp  = ws + OFF_QHP;
    float* qkv  = ws + OFF_QK;
    float* qbv  = ws + OFF_QB;
    float* Sp   = ws + OFF_SP;
    float* att  = ws + OFF_ATT;
    float* ctxp = ws + OFF_CTXP;
    float* con  = ws + OFF_CON;
    float* out  = (float*)d_out;

    k_qh<<<dim3(8, 16), 128, 0, stream>>>(q, Wq, qhp);
    k_qk<<<dim3(16, 8), 128, 0, stream>>>(qhp, bq, Wk, bk, qkv, qbv);
    k_scoresI2<<<dim3(32, 16), 256, 0, stream>>>(k, qkv, qbv, mk, att, Sp);
    k_ctx<<<dim3(256, 4), 256, 0, stream>>>(v, att, ctxp);
    k_outhN<<<dim3(4, NB, 2), 256, 0, stream>>>(ctxp, Sp, Wv, bv, con);
    k_out<<<dim3(4, NB, 2), 256, 0, stream>>>(con, Wo, bo, out);
}

// Round 11
// 284.247 us; speedup vs baseline: 1.0950x; 1.0898x over previous
//
#include <hip/hip_runtime.h>
#include <stdint.h>

#define NB 16
#define NS 4096
#define NH 16
#define NC 1024

// ---- workspace layout (float offsets) ----
#define OFF_QHP   0u          // 262144   qhp[cs16][b][d]
#define OFF_QK    262144u     // 262144   qk[b][h][c]
#define OFF_QB    524288u     // 256      qb[b][h]
#define OFF_SP    524608u     // 8192     Sp[b][sb16][ph32]
#define OFF_CTXP  532800u     // 8388608  ctxp[ss16][p][b][h][c]
#define OFF_CON   8921408u    // 32768    concat[p][b][dm]

// qhp[cs][b][d] = sum_{c in cs-chunk} q[b][c] * Wq[c][d]
__global__ __launch_bounds__(128) void k_qh(
    const float* __restrict__ q, const float* __restrict__ Wq, float* __restrict__ qhp)
{
    __shared__ float qs[64*16];   // [c][b]
    int dz = blockIdx.x, cs = blockIdx.y;
    int tid = threadIdx.x;
    int d = dz*128 + tid;
#pragma unroll
    for (int j = 0; j < 2; ++j) {
        int idx = j*128 + tid;
        int b = idx >> 4, c4 = (idx & 15) << 2;
        float4 t = *(const float4*)(q + (size_t)b*NC + cs*64 + c4);
        qs[(c4+0)*16 + b] = t.x; qs[(c4+1)*16 + b] = t.y;
        qs[(c4+2)*16 + b] = t.z; qs[(c4+3)*16 + b] = t.w;
    }
    __syncthreads();
    float acc[16];
#pragma unroll
    for (int b = 0; b < 16; ++b) acc[b] = 0.f;
#pragma unroll 4
    for (int c = 0; c < 64; ++c) {
        float w = Wq[(size_t)(cs*64 + c)*NC + d];
        const float4* qr = (const float4*)(qs + c*16);
        float4 q0 = qr[0], q1 = qr[1], q2 = qr[2], q3 = qr[3];
        acc[0]  = fmaf(w, q0.x, acc[0]);  acc[1]  = fmaf(w, q0.y, acc[1]);
        acc[2]  = fmaf(w, q0.z, acc[2]);  acc[3]  = fmaf(w, q0.w, acc[3]);
        acc[4]  = fmaf(w, q1.x, acc[4]);  acc[5]  = fmaf(w, q1.y, acc[5]);
        acc[6]  = fmaf(w, q1.z, acc[6]);  acc[7]  = fmaf(w, q1.w, acc[7]);
        acc[8]  = fmaf(w, q2.x, acc[8]);  acc[9]  = fmaf(w, q2.y, acc[9]);
        acc[10] = fmaf(w, q2.z, acc[10]); acc[11] = fmaf(w, q2.w, acc[11]);
        acc[12] = fmaf(w, q3.x, acc[12]); acc[13] = fmaf(w, q3.y, acc[13]);
        acc[14] = fmaf(w, q3.z, acc[14]); acc[15] = fmaf(w, q3.w, acc[15]);
    }
#pragma unroll
    for (int b = 0; b < 16; ++b) qhp[((size_t)cs*16 + b)*NC + d] = acc[b];
}

// qk[b][h][c] = sum_d qh[b][h64+d]*Wk[c][h64+d];  qh = sum_cs qhp + bq. qb = qh_h . bk_h
__global__ __launch_bounds__(128) void k_qk(
    const float* __restrict__ qhp, const float* __restrict__ bq,
    const float* __restrict__ Wk, const float* __restrict__ bk,
    float* __restrict__ qko, float* __restrict__ qbv)
{
    int h = blockIdx.x;
    int c = blockIdx.y*128 + threadIdx.x;
    __shared__ float qs[16*64];   // [b][dd]
    for (int j = 0; j < 8; ++j) {
        int idx = j*128 + threadIdx.x;
        int b = idx >> 6, dd = idx & 63;
        float a = bq[h*64 + dd];
#pragma unroll
        for (int cs = 0; cs < 16; ++cs) a += qhp[((size_t)cs*16 + b)*NC + h*64 + dd];
        qs[idx] = a;
    }
    __syncthreads();
    const float* wr = Wk + (size_t)c*NC + h*64;
    float acc[16];
#pragma unroll
    for (int b = 0; b < 16; ++b) acc[b] = 0.f;
#pragma unroll 4
    for (int d = 0; d < 64; ++d) {
        float w = wr[d];
#pragma unroll
        for (int b = 0; b < 16; ++b) acc[b] = fmaf(qs[b*64 + d], w, acc[b]);
    }
#pragma unroll
    for (int b = 0; b < 16; ++b) qko[((size_t)b*NH + h)*NC + c] = acc[b];
    if (blockIdx.y == 0 && threadIdx.x < 16) {
        int b = threadIdx.x; float a = 0.f;
        for (int d = 0; d < 64; ++d) a = fmaf(qs[b*64 + d], bk[h*64 + d], a);
        qbv[b*NH + h] = a;
    }
}

// Fused flash-style: scores + exp + mask + (att in LDS) + ctx + S.
// grid (sb=16, b=16) = 256 blocks x 512 thr = 1 block/CU, 2 waves/SIMD.
// Phase A: quad owns 8 rows x 4 heads (R10 pattern). att -> LDS (XOR-swizzled).
// Phase B: thread owns c-quad, half-block per 128 rows; v coalesced; LDS reduce.
#define QTS 20
#define SCOMP(BUF, W)                                                          \
    _Pragma("unroll")                                                          \
    for (int j = 0; j < 4; ++j) {                                              \
        const float* qp = qt + ((W)*16 + ph*4 + j)*QTS + hg*4;                 \
        float4 qv = *(const float4*)qp;                                        \
        _Pragma("unroll")                                                      \
        for (int i = 0; i < 8; ++i) {                                          \
            float kc = (j == 0) ? BUF[i].x : (j == 1) ? BUF[i].y               \
                     : (j == 2) ? BUF[i].z : BUF[i].w;                         \
            acc[i][0] = fmaf(kc, qv.x, acc[i][0]);                             \
            acc[i][1] = fmaf(kc, qv.y, acc[i][1]);                             \
            acc[i][2] = fmaf(kc, qv.z, acc[i][2]);                             \
            acc[i][3] = fmaf(kc, qv.w, acc[i][3]);                             \
        }                                                                      \
    }
__global__ __launch_bounds__(512) void k_att(
    const float* __restrict__ kk, const float* __restrict__ vv,
    const float* __restrict__ qkm, const float* __restrict__ qbv,
    const void* __restrict__ mask, float* __restrict__ ctxp, float* __restrict__ Sp)
{
    __shared__ float qt[512*QTS];     // 40 KB: q-stage, reused as reduce buf
    __shared__ float attl[256*32];    // 32 KB, XOR-swizzled by row
    __shared__ float red[8][2][16];
    int sb = blockIdx.x, b = blockIdx.y;
    int tid = threadIdx.x;
    int ph = tid & 3, hg = (tid >> 2) & 3, rg = tid >> 4;  // rg in [0,32)
    int srow = sb*256 + rg*8;

    // inline mask dtype probe: 0=int32, 1=bytes, 2=float32
    int fl;
    {
        const uint4* mw = (const uint4*)mask;
        unsigned f = 0u, g = 0u;
#pragma unroll
        for (int j = 0; j < 8; ++j) {
            uint4 m4 = mw[j];
            f |= (m4.x == 0x3F800000u) | (m4.y == 0x3F800000u)
               | (m4.z == 0x3F800000u) | (m4.w == 0x3F800000u);
            g |= ((m4.x > 1u) & (m4.x != 0x3F800000u))
               | ((m4.y > 1u) & (m4.y != 0x3F800000u))
               | ((m4.z > 1u) & (m4.z != 0x3F800000u))
               | ((m4.w > 1u) & (m4.w != 0x3F800000u));
        }
        fl = f ? 2 : (g ? 1 : 0);
    }

    // ---------- Phase A: scores ----------
    const float* kr = kk + ((size_t)b*NS + srow)*NC + ph*4;
    float acc[8][4];
#pragma unroll
    for (int i = 0; i < 8; ++i)
#pragma unroll
        for (int j = 0; j < 4; ++j) acc[i][j] = 0.f;

    for (int cz = 0; cz < 2; ++cz) {
        __syncthreads();
#pragma unroll
        for (int j = 0; j < 16; ++j) {        // stage 512c x 16h
            int idx = j*512 + tid;
            int h = idx >> 9, c = idx & 511;
            qt[c*QTS + h] = qkm[((size_t)b*NH + h)*NC + cz*512 + c];
        }
        __syncthreads();
        const float* kc0 = kr + cz*512;
        float4 kv[8], kn[8];
#pragma unroll
        for (int i = 0; i < 8; ++i) kv[i] = *(const float4*)(kc0 + i*NC);
        for (int w = 0; w < 32; ++w) {
            if (w < 31) {
#pragma unroll
                for (int i = 0; i < 8; ++i)
                    kn[i] = *(const float4*)(kc0 + i*NC + (w+1)*16);
            }
            SCOMP(kv, w);
#pragma unroll
            for (int i = 0; i < 8; ++i) kv[i] = kn[i];
        }
    }
#pragma unroll
    for (int i = 0; i < 8; ++i)
#pragma unroll
        for (int j = 0; j < 4; ++j) {
            acc[i][j] += __shfl_xor(acc[i][j], 1, 64);
            acc[i][j] += __shfl_xor(acc[i][j], 2, 64);
        }
    float d0[4], d1[4];
    if (ph == 0) {
#pragma unroll
        for (int j = 0; j < 4; ++j) { d0[j] = acc[0][j]; d1[j] = acc[1][j]; }
    } else if (ph == 1) {
#pragma unroll
        for (int j = 0; j < 4; ++j) { d0[j] = acc[2][j]; d1[j] = acc[3][j]; }
    } else if (ph == 2) {
#pragma unroll
        for (int j = 0; j < 4; ++j) { d0[j] = acc[4][j]; d1[j] = acc[5][j]; }
    } else {
#pragma unroll
        for (int j = 0; j < 4; ++j) { d0[j] = acc[6][j]; d1[j] = acc[7][j]; }
    }
    int lA = rg*8 + 2*ph, lB = lA + 1;
    int sA = sb*256 + lA, sB = sA + 1;
    unsigned mA = 0, mB = 0;
    if (fl == 1) {
        const uint8_t* mp = (const uint8_t*)mask + (size_t)(b*NH + hg*4)*NS;
#pragma unroll
        for (int j = 0; j < 4; ++j) {
            if (mp[(size_t)j*NS + sA]) mA |= (1u << j);
            if (mp[(size_t)j*NS + sB]) mB |= (1u << j);
        }
    } else if (fl == 2) {
        const float* mp = (const float*)mask + (size_t)(b*NH + hg*4)*NS;
#pragma unroll
        for (int j = 0; j < 4; ++j) {
            if (mp[(size_t)j*NS + sA] != 0.f) mA |= (1u << j);
            if (mp[(size_t)j*NS + sB] != 0.f) mB |= (1u << j);
        }
    } else {
        const int* mp = (const int*)mask + (size_t)(b*NH + hg*4)*NS;
#pragma unroll
        for (int j = 0; j < 4; ++j) {
            if (mp[(size_t)j*NS + sA]) mA |= (1u << j);
            if (mp[(size_t)j*NS + sB]) mB |= (1u << j);
        }
    }
    float p0a[4], p1a[4], p0b[4], p1b[4], r0[4], r1[4];
#pragma unroll
    for (int j = 0; j < 4; ++j) {
        float qb = qbv[b*NH + hg*4 + j];
        float va = (d0[j] + qb) * 0.125f;
        float vb = (d1[j] + qb) * 0.125f;
        p0a[j] = __expf(va);  p1a[j] = (mA >> j & 1u) ? 1.0f : p0a[j];
        p0b[j] = __expf(vb);  p1b[j] = (mB >> j & 1u) ? 1.0f : p0b[j];
        r0[j] = p0a[j] + p0b[j];
        r1[j] = p1a[j] + p1b[j];
    }
    // att -> LDS, XOR-swizzled: float u of row l lives at attl[l*32 + (u ^ ((l&7)<<2))]
    {
        int swA = (lA & 7) << 2, swB = (lB & 7) << 2;
        *(float4*)(attl + lA*32 + ((hg*4) ^ swA))        = make_float4(p0a[0], p0a[1], p0a[2], p0a[3]);
        *(float4*)(attl + lA*32 + ((16 + hg*4) ^ swA))   = make_float4(p1a[0], p1a[1], p1a[2], p1a[3]);
        *(float4*)(attl + lB*32 + ((hg*4) ^ swB))        = make_float4(p0b[0], p0b[1], p0b[2], p0b[3]);
        *(float4*)(attl + lB*32 + ((16 + hg*4) ^ swB))   = make_float4(p1b[0], p1b[1], p1b[2], p1b[3]);
    }
    // S partials: xor {1,2} over ph, {16,32} over rg-in-wave, LDS over 8 waves
#pragma unroll
    for (int j = 0; j < 4; ++j) {
        r0[j] += __shfl_xor(r0[j], 1, 64);  r1[j] += __shfl_xor(r1[j], 1, 64);
        r0[j] += __shfl_xor(r0[j], 2, 64);  r1[j] += __shfl_xor(r1[j], 2, 64);
        r0[j] += __shfl_xor(r0[j], 16, 64); r1[j] += __shfl_xor(r1[j], 16, 64);
        r0[j] += __shfl_xor(r0[j], 32, 64); r1[j] += __shfl_xor(r1[j], 32, 64);
    }
    int wv = tid >> 6;
    if ((tid & 51) == 0) {
#pragma unroll
        for (int j = 0; j < 4; ++j) {
            red[wv][0][hg*4 + j] = r0[j];
            red[wv][1][hg*4 + j] = r1[j];
        }
    }
    __syncthreads();     // red + attl ready
    if (tid < 32) {
        int pa = tid >> 4, h = tid & 15;
        float a = 0.f;
#pragma unroll
        for (int w8 = 0; w8 < 8; ++w8) a += red[w8][pa][h];
        Sp[((size_t)b*16 + sb)*32 + tid] = a;
    }

    // ---------- Phase B: ctx ----------
    int cq = tid & 255, half = tid >> 8;
    float cacc[32][4];
#pragma unroll
    for (int u = 0; u < 32; ++u)
#pragma unroll
        for (int j = 0; j < 4; ++j) cacc[u][j] = 0.f;
    const float* vb = vv + ((size_t)b*NS + sb*256 + half*128)*NC + cq*4;
    for (int r = 0; r < 128; ++r) {
        float4 vvv = *(const float4*)(vb + (size_t)r*NC);
        int l = half*128 + r;
        const float* ar = attl + l*32;
        int lw = l & 7;
#pragma unroll
        for (int g = 0; g < 8; ++g) {
            float4 aw = *(const float4*)(ar + ((g ^ lw) << 2));
            cacc[g*4+0][0] = fmaf(aw.x, vvv.x, cacc[g*4+0][0]);
            cacc[g*4+0][1] = fmaf(aw.x, vvv.y, cacc[g*4+0][1]);
            cacc[g*4+0][2] = fmaf(aw.x, vvv.z, cacc[g*4+0][2]);
            cacc[g*4+0][3] = fmaf(aw.x, vvv.w, cacc[g*4+0][3]);
            cacc[g*4+1][0] = fmaf(aw.y, vvv.x, cacc[g*4+1][0]);
            cacc[g*4+1][1] = fmaf(aw.y, vvv.y, cacc[g*4+1][1]);
            cacc[g*4+1][2] = fmaf(aw.y, vvv.z, cacc[g*4+1][2]);
            cacc[g*4+1][3] = fmaf(aw.y, vvv.w, cacc[g*4+1][3]);
            cacc[g*4+2][0] = fmaf(aw.z, vvv.x, cacc[g*4+2][0]);
            cacc[g*4+2][1] = fmaf(aw.z, vvv.y, cacc[g*4+2][1]);
            cacc[g*4+2][2] = fmaf(aw.z, vvv.z, cacc[g*4+2][2]);
            cacc[g*4+2][3] = fmaf(aw.z, vvv.w, cacc[g*4+2][3]);
            cacc[g*4+3][0] = fmaf(aw.w, vvv.x, cacc[g*4+3][0]);
            cacc[g*4+3][1] = fmaf(aw.w, vvv.y, cacc[g*4+3][1]);
            cacc[g*4+3][2] = fmaf(aw.w, vvv.z, cacc[g*4+3][2]);
            cacc[g*4+3][3] = fmaf(aw.w, vvv.w, cacc[g*4+3][3]);
        }
    }
    // cross-half reduce via qt (reuse), 4 rounds x 8 ph; half0 writes ctxp slab
    float* buf = qt;
#pragma unroll
    for (int pr = 0; pr < 4; ++pr) {
        __syncthreads();
        if (half == 1) {
#pragma unroll
            for (int u = 0; u < 8; ++u)
                *(float4*)(buf + (u*256 + cq)*4) =
                    make_float4(cacc[pr*8+u][0], cacc[pr*8+u][1],
                                cacc[pr*8+u][2], cacc[pr*8+u][3]);
        }
        __syncthreads();
        if (half == 0) {
#pragma unroll
            for (int u = 0; u < 8; ++u) {
                float4 t = *(const float4*)(buf + (u*256 + cq)*4);
                int uph = pr*8 + u, p = uph >> 4, h = uph & 15;
                float4 s;
                s.x = cacc[pr*8+u][0] + t.x; s.y = cacc[pr*8+u][1] + t.y;
                s.z = cacc[pr*8+u][2] + t.z; s.w = cacc[pr*8+u][3] + t.w;
                *(float4*)(ctxp + ((((size_t)sb*2 + p)*NB + b)*NH + h)*NC + cq*4) = s;
            }
        }
    }
}

// Fused: slab-reduce ctxp + S-normalize + Wv GEMV + bias -> concat[p][b][d]
__global__ __launch_bounds__(256) void k_outhN(
    const float* __restrict__ ctxp, const float* __restrict__ Sp,
    const float* __restrict__ Wv, const float* __restrict__ bv,
    float* __restrict__ con)
{
    int b = blockIdx.y, p = blockIdx.z;
    int dx = blockIdx.x;
    int d = dx*256 + threadIdx.x;
    int h0 = dx*4;
    __shared__ float cl[4*NC];
    float Sinv[4];
#pragma unroll
    for (int j = 0; j < 4; ++j) {
        float a = 0.f;
        for (int sb = 0; sb < 16; ++sb)
            a += Sp[((size_t)b*16 + sb)*32 + p*16 + h0 + j];
        Sinv[j] = 1.f / a;
    }
#pragma unroll
    for (int hh = 0; hh < 4; ++hh) {
        for (int cc = threadIdx.x; cc < NC; cc += 256) {
            float a = 0.f;
#pragma unroll
            for (int ss = 0; ss < 16; ++ss)
                a += ctxp[((((size_t)ss*2 + p)*NB + b)*NH + h0 + hh)*NC + cc];
            cl[hh*NC + cc] = a * Sinv[hh];
        }
    }
    __syncthreads();
    const float* c2 = cl + ((threadIdx.x >> 6) << 10);
    float a0=0.f,a1=0.f,a2=0.f,a3=0.f;
    for (int c = 0; c < NC; c += 4) {
        a0 = fmaf(c2[c+0], Wv[(size_t)(c+0)*NC + d], a0);
        a1 = fmaf(c2[c+1], Wv[(size_t)(c+1)*NC + d], a1);
        a2 = fmaf(c2[c+2], Wv[(size_t)(c+2)*NC + d], a2);
        a3 = fmaf(c2[c+3], Wv[(size_t)(c+3)*NC + d], a3);
    }
    con[((size_t)p*NB + b)*NC + d] = (a0+a1)+(a2+a3) + bv[d];
}

// out[p][b][o] = concat[p][b][:] . Wo[:, o] + bo[o]
__global__ __launch_bounds__(256) void k_out(
    const float* __restrict__ con, const float* __restrict__ Wo,
    const float* __restrict__ bo, float* __restrict__ out)
{
    int b = blockIdx.y, p = blockIdx.z;
    int o = blockIdx.x*256 + threadIdx.x;
    __shared__ float cl[NC];
    for (int i = threadIdx.x; i < NC; i += 256)
        cl[i] = con[((size_t)p*NB + b)*NC + i];
    __syncthreads();
    float a0=0.f,a1=0.f,a2=0.f,a3=0.f;
    for (int m = 0; m < NC; m += 4) {
        a0 = fmaf(cl[m+0], Wo[(size_t)(m+0)*NC + o], a0);
        a1 = fmaf(cl[m+1], Wo[(size_t)(m+1)*NC + o], a1);
        a2 = fmaf(cl[m+2], Wo[(size_t)(m+2)*NC + o], a2);
        a3 = fmaf(cl[m+3], Wo[(size_t)(m+3)*NC + o], a3);
    }
    out[(size_t)p*NB*NC + (size_t)b*NC + o] = (a0+a1)+(a2+a3) + bo[o];
}

extern "C" void kernel_launch(void* const* d_in, const int* in_sizes, int n_in,
                              void* d_out, int out_size, void* d_ws, size_t ws_size,
                              hipStream_t stream)
{
    (void)in_sizes; (void)n_in; (void)out_size; (void)ws_size;
    const float* q  = (const float*)d_in[0];
    const float* k  = (const float*)d_in[1];
    const float* v  = (const float*)d_in[2];
    const float* Wq = (const float*)d_in[3];
    const float* bq = (const float*)d_in[4];
    const float* Wk = (const float*)d_in[5];
    const float* bk = (const float*)d_in[6];
    const float* Wv = (const float*)d_in[7];
    const float* bv = (const float*)d_in[8];
    const float* Wo = (const float*)d_in[9];
    const float* bo = (const float*)d_in[10];
    const void*  mk = d_in[11];

    float* ws   = (float*)d_ws;
    float* qhp  = ws + OFF_QHP;
    float* qkv  = ws + OFF_QK;
    float* qbv  = ws + OFF_QB;
    float* Sp   = ws + OFF_SP;
    float* ctxp = ws + OFF_CTXP;
    float* con  = ws + OFF_CON;
    float* out  = (float*)d_out;

    k_qh<<<dim3(8, 16), 128, 0, stream>>>(q, Wq, qhp);
    k_qk<<<dim3(16, 8), 128, 0, stream>>>(qhp, bq, Wk, bk, qkv, qbv);
    k_att<<<dim3(16, 16), 512, 0, stream>>>(k, v, qkv, qbv, mk, ctxp, Sp);
    k_outhN<<<dim3(4, NB, 2), 256, 0, stream>>>(ctxp, Sp, Wv, bv, con);
    k_out<<<dim3(4, NB, 2), 256, 0, stream>>>(con, Wo, bo, out);
}